// Round 2
// baseline (161.982 us; speedup 1.0000x reference)
//
#include <hip/hip_runtime.h>

// LSTM: B=16384 sequences, T=1024 steps, I=1, H=2, C=4.
// 1 thread per batch element; the whole recurrence lives in registers.
// Gate order (PyTorch): i (k=0,1), f (k=2,3), g (k=4,5), o (k=6,7).
//
// Nonlinearity formulation (merged reciprocals, raw v_exp_f32 / v_rcp_f32):
//   E_k = exp2(s_k * pre_k),  s_k = -log2(e) for i,f,o ;  +2*log2(e) for g
//   c' = [c*(1+Ei)(Eg+1) + (Eg-1)(1+Ef)] / [(1+Ef)(1+Ei)(Eg+1)]     (1 rcp)
//   h' = (Ec-1) / [(1+Eo)(Ec+1)],  Ec = exp2(clamp(2log2e * c', +-30)) (1 rcp)
// => 10 exp2 + 4 rcp per element-step (vs 20 trans naive).

static __device__ __forceinline__ float fast_exp2(float x) { return __builtin_amdgcn_exp2f(x); }
static __device__ __forceinline__ float fast_rcp(float x)  { return __builtin_amdgcn_rcpf(x); }

#define SIG_SCALE  (-1.4426950408889634f)  // -log2(e)
#define TANH_SCALE ( 2.8853900817779268f)  // 2*log2(e)

__global__ __launch_bounds__(64, 1) void lstm_fused(
    const float* __restrict__ x,      // [B, T, 1]
    const float* __restrict__ W_ih,   // [8, 1]
    const float* __restrict__ W_hh,   // [8, 2]
    const float* __restrict__ b_ih,   // [8]
    const float* __restrict__ b_hh,   // [8]
    const float* __restrict__ W_fc,   // [4, 2]
    const float* __restrict__ b_fc,   // [4]
    float* __restrict__ out,          // [B, 4]
    int T)
{
    const int b = blockIdx.x * 64 + threadIdx.x;

    // Fold the exp2 scale factors into the weights once per thread
    // (uniform loads -> scalar cache; amortized over 1024 steps).
    float wih[8], wh0[8], wh1[8], bb[8];
#pragma unroll
    for (int k = 0; k < 8; ++k) {
        const float s = (k == 4 || k == 5) ? TANH_SCALE : SIG_SCALE;
        wih[k] = s * W_ih[k];
        wh0[k] = s * W_hh[2 * k + 0];
        wh1[k] = s * W_hh[2 * k + 1];
        bb[k]  = s * (b_ih[k] + b_hh[k]);
    }

    float h0 = 0.f, h1 = 0.f, c0 = 0.f, c1 = 0.f;

    const float4* xv = reinterpret_cast<const float4*>(x + (size_t)b * (size_t)T);
    const int nt4 = T >> 2;

    for (int t4 = 0; t4 < nt4; ++t4) {
        const float4 xq = xv[t4];
        float xs[4] = {xq.x, xq.y, xq.z, xq.w};

        // x-terms for all 4 timesteps up front: h-independent ILP the
        // scheduler can overlap with the recurrent chain.
        float xterm[4][8];
#pragma unroll
        for (int u = 0; u < 4; ++u)
#pragma unroll
            for (int k = 0; k < 8; ++k)
                xterm[u][k] = fmaf(xs[u], wih[k], bb[k]);

#pragma unroll
        for (int u = 0; u < 4; ++u) {
            float E[8];
#pragma unroll
            for (int k = 0; k < 8; ++k) {
                const float pre = fmaf(wh0[k], h0, fmaf(wh1[k], h1, xterm[u][k]));
                E[k] = fast_exp2(pre);
            }
#pragma unroll
            for (int j = 0; j < 2; ++j) {
                const float Ei = E[0 + j], Ef = E[2 + j], Eg = E[4 + j], Eo = E[6 + j];
                float c = j ? c1 : c0;

                const float F   = 1.f + Ef;
                const float Gp  = 1.f + Eg;
                const float P   = fmaf(Ei, Gp, Gp);            // (1+Ei)(1+Eg)
                const float GmF = fmaf(Eg, F, -F);             // (Eg-1)(1+Ef)
                const float num = fmaf(c, P, GmF);
                const float den = F * P;
                c = num * fast_rcp(den);

                const float a  = fminf(fmaxf(TANH_SCALE * c, -30.f), 30.f);
                const float Ec = fast_exp2(a);
                const float dh = (1.f + Eo) * (Ec + 1.f);
                const float r  = fast_rcp(dh);
                const float h  = fmaf(Ec, r, -r);              // (Ec-1)/dh

                if (j) { c1 = c; h1 = h; } else { c0 = c; h0 = h; }
            }
        }
    }

    // Final FC: out[b, :] = h @ W_fc^T + b_fc   (C=4, H=2)
    const float o0 = fmaf(W_fc[0], h0, fmaf(W_fc[1], h1, b_fc[0]));
    const float o1 = fmaf(W_fc[2], h0, fmaf(W_fc[3], h1, b_fc[1]));
    const float o2 = fmaf(W_fc[4], h0, fmaf(W_fc[5], h1, b_fc[2]));
    const float o3 = fmaf(W_fc[6], h0, fmaf(W_fc[7], h1, b_fc[3]));
    float4 r4; r4.x = o0; r4.y = o1; r4.z = o2; r4.w = o3;
    reinterpret_cast<float4*>(out)[b] = r4;
}

extern "C" void kernel_launch(void* const* d_in, const int* in_sizes, int n_in,
                              void* d_out, int out_size, void* d_ws, size_t ws_size,
                              hipStream_t stream) {
    const float* x    = (const float*)d_in[0];
    const float* W_ih = (const float*)d_in[1];
    const float* W_hh = (const float*)d_in[2];
    const float* b_ih = (const float*)d_in[3];
    const float* b_hh = (const float*)d_in[4];
    const float* W_fc = (const float*)d_in[5];
    const float* b_fc = (const float*)d_in[6];
    float* out = (float*)d_out;

    const int T = 1024;
    const int B = in_sizes[0] / T;   // I == 1

    dim3 block(64);
    dim3 grid(B / 64);               // B = 16384 -> 256 blocks, 1 wave/CU
    lstm_fused<<<grid, block, 0, stream>>>(x, W_ih, W_hh, b_ih, b_hh, W_fc, b_fc, out, T);
}

// Round 3
// 161.036 us; speedup vs baseline: 1.0059x; 1.0059x over previous
//
#include <hip/hip_runtime.h>

// LSTM: B=16384 sequences, T=1024 steps, I=1, H=2, C=4.
// 1 thread per batch element; the whole recurrence lives in registers.
// Gate order (PyTorch): i (k=0,1), f (k=2,3), g (k=4,5), o (k=6,7).
//
// Nonlinearity formulation (merged reciprocals, raw v_exp_f32 / v_rcp_f32):
//   E_k = exp2(s_k * pre_k),  s_k = -log2(e) for i,f,o ;  +2*log2(e) for g
//   c' = [c*(1+Ei)(Eg+1) + (Eg-1)(1+Ef)] / [(1+Ef)(1+Ei)(Eg+1)]     (1 rcp)
//   h' = (Ec-1) / [(1+Eo)(Ec+1)],  Ec = exp2(clamp(2log2e * c', +-30)) (1 rcp)
// => 10 exp2 + 4 rcp per element-step (vs 20 trans naive).

static __device__ __forceinline__ float fast_exp2(float x) { return __builtin_amdgcn_exp2f(x); }
static __device__ __forceinline__ float fast_rcp(float x)  { return __builtin_amdgcn_rcpf(x); }

#define SIG_SCALE  (-1.4426950408889634f)  // -log2(e)
#define TANH_SCALE ( 2.8853900817779268f)  // 2*log2(e)

__global__ __launch_bounds__(64, 1) void lstm_fused(
    const float* __restrict__ x,      // [B, T, 1]
    const float* __restrict__ W_ih,   // [8, 1]
    const float* __restrict__ W_hh,   // [8, 2]
    const float* __restrict__ b_ih,   // [8]
    const float* __restrict__ b_hh,   // [8]
    const float* __restrict__ W_fc,   // [4, 2]
    const float* __restrict__ b_fc,   // [4]
    float* __restrict__ out,          // [B, 4]
    int T)
{
    const int b = blockIdx.x * 64 + threadIdx.x;

    // Fold the exp2 scale factors into the weights once per thread
    // (uniform loads -> scalar cache; amortized over 1024 steps).
    float wih[8], wh0[8], wh1[8], bb[8];
#pragma unroll
    for (int k = 0; k < 8; ++k) {
        const float s = (k == 4 || k == 5) ? TANH_SCALE : SIG_SCALE;
        wih[k] = s * W_ih[k];
        wh0[k] = s * W_hh[2 * k + 0];
        wh1[k] = s * W_hh[2 * k + 1];
        bb[k]  = s * (b_ih[k] + b_hh[k]);
    }

    float h0 = 0.f, h1 = 0.f, c0 = 0.f, c1 = 0.f;

    const float4* xv = reinterpret_cast<const float4*>(x + (size_t)b * (size_t)T);
    const int nt4 = T >> 2;

    for (int t4 = 0; t4 < nt4; ++t4) {
        const float4 xq = xv[t4];
        float xs[4] = {xq.x, xq.y, xq.z, xq.w};

        // x-terms for all 4 timesteps up front: h-independent ILP the
        // scheduler can overlap with the recurrent chain.
        float xterm[4][8];
#pragma unroll
        for (int u = 0; u < 4; ++u)
#pragma unroll
            for (int k = 0; k < 8; ++k)
                xterm[u][k] = fmaf(xs[u], wih[k], bb[k]);

#pragma unroll
        for (int u = 0; u < 4; ++u) {
            float E[8];
#pragma unroll
            for (int k = 0; k < 8; ++k) {
                const float pre = fmaf(wh0[k], h0, fmaf(wh1[k], h1, xterm[u][k]));
                E[k] = fast_exp2(pre);
            }
#pragma unroll
            for (int j = 0; j < 2; ++j) {
                const float Ei = E[0 + j], Ef = E[2 + j], Eg = E[4 + j], Eo = E[6 + j];
                float c = j ? c1 : c0;

                const float F   = 1.f + Ef;
                const float Gp  = 1.f + Eg;
                const float P   = fmaf(Ei, Gp, Gp);            // (1+Ei)(1+Eg)
                const float GmF = fmaf(Eg, F, -F);             // (Eg-1)(1+Ef)
                const float num = fmaf(c, P, GmF);
                const float den = F * P;
                c = num * fast_rcp(den);

                const float a  = fminf(fmaxf(TANH_SCALE * c, -30.f), 30.f);
                const float Ec = fast_exp2(a);
                const float dh = (1.f + Eo) * (Ec + 1.f);
                const float r  = fast_rcp(dh);
                const float h  = fmaf(Ec, r, -r);              // (Ec-1)/dh

                if (j) { c1 = c; h1 = h; } else { c0 = c; h0 = h; }
            }
        }
    }

    // Final FC: out[b, :] = h @ W_fc^T + b_fc   (C=4, H=2)
    const float o0 = fmaf(W_fc[0], h0, fmaf(W_fc[1], h1, b_fc[0]));
    const float o1 = fmaf(W_fc[2], h0, fmaf(W_fc[3], h1, b_fc[1]));
    const float o2 = fmaf(W_fc[4], h0, fmaf(W_fc[5], h1, b_fc[2]));
    const float o3 = fmaf(W_fc[6], h0, fmaf(W_fc[7], h1, b_fc[3]));
    float4 r4; r4.x = o0; r4.y = o1; r4.z = o2; r4.w = o3;
    reinterpret_cast<float4*>(out)[b] = r4;
}

extern "C" void kernel_launch(void* const* d_in, const int* in_sizes, int n_in,
                              void* d_out, int out_size, void* d_ws, size_t ws_size,
                              hipStream_t stream) {
    const float* x    = (const float*)d_in[0];
    const float* W_ih = (const float*)d_in[1];
    const float* W_hh = (const float*)d_in[2];
    const float* b_ih = (const float*)d_in[3];
    const float* b_hh = (const float*)d_in[4];
    const float* W_fc = (const float*)d_in[5];
    const float* b_fc = (const float*)d_in[6];
    float* out = (float*)d_out;

    const int T = 1024;
    const int B = in_sizes[0] / T;   // I == 1

    dim3 block(64);
    dim3 grid(B / 64);               // B = 16384 -> 256 blocks, 1 wave/CU
    lstm_fused<<<grid, block, 0, stream>>>(x, W_ih, W_hh, b_ih, b_hh, W_fc, b_fc, out, T);
}